// Round 5
// baseline (883.463 us; speedup 1.0000x reference)
//
#include <hip/hip_runtime.h>

#define H 181
#define T_LEN 1024
#define BB 4             // batch rows per block
#define NBLK 256         // 256 * 4 = 1024; one block per CU (LDS-pinned)
#define NTHR 256         // R18: 4 waves, exactly 1 per SIMD
#define TPW 3            // unit-tiles per wave: 4 waves * 3 * 16 = 192 >= 181
#define KT3 3            // k-tiles of 64 -> 192 >= 181
#define FRAGB 1024       // bytes per kt fragment (64 lanes x 16 B)
#define PST 192          // unit stride (wsc, FC)
#define XSTR 1027        // x_s stride (odd -> broadcast reads conflict-free)

typedef __attribute__((ext_vector_type(4))) int intx4;

#define LOG2E 1.4426950408889634f
// Schraudolph exp2 (balanced sawtooth, |rel err| <= ~3%), clamped to [-20,14]
#define SCH_C  1064992506.0f
#define SCH_LO 897220352.0f
#define SCH_HI 1182433024.0f

__device__ __forceinline__ float exp2_fast(float g) {
    float s = fmaf(g, 8388608.0f, SCH_C);
    s = fminf(fmaxf(s, SCH_LO), SCH_HI);
    return __uint_as_float((unsigned)s);
}
__device__ __forceinline__ float rcpf(float x)   { return __builtin_amdgcn_rcpf(x); }
__device__ __forceinline__ float exp2hw(float x) { return __builtin_amdgcn_exp2f(x); }

// R22 == R18 resubmit (broker timeout 5 rounds running; never measured).
// R18: R17 numerics bit-identical; structure change 12 waves -> 4 waves.
// Theory: 12 waves all read ALL 3 bf fragments (36 ds_read_b128/CU/step
// ~ 430-580 cy of LDS pipe at m134's ~12cy/b128) + 3-wave/SIMD issue
// arbitration + 12-wave barrier skew = the ~1660 cy/step. With 4 waves
// (1/SIMD, 3 unit-tiles each) total MFMA/VALU per CU is unchanged but LDS
// reads /3, barrier population /3, no same-SIMD arbitration. afr becomes
// 27 intx4 = 108 VGPRs (launch_bounds(256,1) -> up to 512, no spill).
// Structure: 256 blocks x 4 batch, 4 waves; wave jt owns unit-tiles
// jt*3..jt*3+2 for all 3 gates (27 mfma_i32_16x16x64_i8/step); DPP
// redistribute to dense per-lane (unit,batch) triples; gates r=Schraudolph,
// z/n=exact exp; DPP gather + perm pack; leader b32 write; ONE barrier/step.
__launch_bounds__(NTHR, 1)
__global__ void gru_i8(const float* __restrict__ x,
                       const float* __restrict__ w_ih,
                       const float* __restrict__ w_hh,
                       const float* __restrict__ b_ih,
                       const float* __restrict__ b_hh,
                       const float* __restrict__ w_fc,
                       const float* __restrict__ b_fc,
                       float* __restrict__ out) {
    __shared__ __align__(16) char  hfr_s[2 * KT3 * FRAGB];  // 6 KB i8 h dbuf
    __shared__ __align__(16) float x_s[BB * XSTR];          // 16 KB x; reused for FC
    __shared__ float wsc_s[3 * PST];                        // w_hh row scales
    __shared__ volatile char pad_s[57344];                  // total > 80 KB: pin 1 block/CU

    const int tid  = threadIdx.x;
    const int jt   = tid >> 6;          // wave 0..3
    const int lane = tid & 63;
    const int col  = lane & 15;
    const int q    = lane >> 4;
    const int b0   = blockIdx.x * BB;
    if (tid == 0) pad_s[0] = 0;

    // ---- A fragments: per-row int8 w_hh, 3 gates x 3 tiles x 3 kt ----
    // Built entirely in registers: dword = b0 | b1<<8 | b2<<16 | b3<<24.
    intx4 afr[3][TPW][KT3];
    #pragma unroll
    for (int tl = 0; tl < TPW; ++tl) {
        const int  tt = jt * TPW + tl;
        const int  mu = tt * 16 + col;
        const bool mv = (mu < H);
        #pragma unroll
        for (int g = 0; g < 3; ++g) {
            const float* wrow = w_hh + (size_t)(g * H + (mv ? mu : 0)) * H;
            float rm = 0.0f;
            if (mv) for (int k = 0; k < H; ++k) rm = fmaxf(rm, fabsf(wrow[k]));
            float s    = (rm > 1e-30f) ? rm * (1.0f / 127.0f) : 1.0f;
            float invs = 1.0f / s;
            #pragma unroll
            for (int kt = 0; kt < KT3; ++kt) {
                intx4 frag;
                #pragma unroll
                for (int w = 0; w < 4; ++w) {
                    int dw = 0;
                    #pragma unroll
                    for (int e = 0; e < 4; ++e) {
                        int k = kt * 64 + q * 16 + w * 4 + e;
                        float v = (mv && k < H) ? wrow[k] * invs : 0.0f;
                        v = fminf(fmaxf(rintf(v), -127.0f), 127.0f);
                        int iv = (int)v;
                        dw |= (iv & 255) << (8 * e);
                    }
                    frag[w] = dw;
                }
                afr[g][tl][kt] = frag;
            }
            if (q == 0) wsc_s[g * PST + mu] = s;
        }
    }

    // ---- stage x (stride 1027); zero h frag buffers ----
    for (int i = tid; i < BB * T_LEN; i += NTHR) {
        int bb = i >> 10, t = i & 1023;
        x_s[bb * XSTR + t] = x[(size_t)b0 * T_LEN + i];
    }
    {
        int* hz = (int*)hfr_s;
        for (int i = tid; i < 2 * KT3 * FRAGB / 4; i += NTHR) hz[i] = 0;
    }
    __syncthreads();   // wsc_s ready

    // ---- dense per-lane identity after DPP redistribute (3 tiles/lane) ----
    const int rr4 = (col >> 2) & 3;       // reg index this lane receives
    const int b   = col & 3;              // batch
    float dqR[TPW], dqZ[TPW], dqN[TPW];
    float baseR[TPW], baseZ[TPW], baseN[TPW];
    float wrS[TPW], wzS[TPW], wnS[TPW], bnI[TPW];
    int   woff[TPW];
    int   uu[TPW];
    bool  jv[TPW];
    #pragma unroll
    for (int tl = 0; tl < TPW; ++tl) {
        const int tt = jt * TPW + tl;
        const int u  = tt * 16 + q * 4 + rr4;   // unit
        uu[tl] = u;
        jv[tl] = (u < H);
        dqR[tl] = -LOG2E * wsc_s[0 * PST + u] * (1.0f / 127.0f);
        dqZ[tl] = -LOG2E * wsc_s[1 * PST + u] * (1.0f / 127.0f);
        dqN[tl] =  2.0f * LOG2E * wsc_s[2 * PST + u] * (1.0f / 127.0f);
        baseR[tl] = jv[tl] ? -LOG2E * (b_ih[u] + b_hh[u])             : 0.0f;
        baseZ[tl] = jv[tl] ? -LOG2E * (b_ih[H + u] + b_hh[H + u])     : 0.0f;
        baseN[tl] = jv[tl] ?  2.0f * LOG2E * b_hh[2 * H + u]          : 0.0f;
        wrS[tl] = jv[tl] ? -LOG2E * w_ih[u]                : 0.0f;
        wzS[tl] = jv[tl] ? -LOG2E * w_ih[H + u]            : 0.0f;
        wnS[tl] = jv[tl] ?  2.0f * LOG2E * w_ih[2 * H + u] : 0.0f;
        bnI[tl] = jv[tl] ?  2.0f * LOG2E * b_ih[2 * H + u] : 0.0f;
        // leader (rr4==0) packs 4 units' bytes and writes one b32
        woff[tl] = (tt >> 2) * FRAGB + (((tt & 3) * 16 + b) * 16) + q * 4;
    }
    const int rbase = lane * 16;

    float h[TPW] = {0.0f, 0.0f, 0.0f};

    auto step = [&](const char* rb, char* wb, int t) {
        intx4 bf[KT3];
        #pragma unroll
        for (int kt = 0; kt < KT3; ++kt)
            bf[kt] = *(const intx4*)(rb + kt * FRAGB + rbase);
        float xv = x_s[b * XSTR + t];

        // ---- all MFMAs first: 9 independent accumulator chains ----
        intx4 aR[TPW], aZ[TPW], aN[TPW];
        #pragma unroll
        for (int tl = 0; tl < TPW; ++tl) {
            intx4 zR = {0, 0, 0, 0}, zZ = {0, 0, 0, 0}, zN = {0, 0, 0, 0};
            #pragma unroll
            for (int kt = 0; kt < KT3; ++kt) {
                zR = __builtin_amdgcn_mfma_i32_16x16x64_i8(afr[0][tl][kt], bf[kt], zR, 0, 0, 0);
                zZ = __builtin_amdgcn_mfma_i32_16x16x64_i8(afr[1][tl][kt], bf[kt], zZ, 0, 0, 0);
                zN = __builtin_amdgcn_mfma_i32_16x16x64_i8(afr[2][tl][kt], bf[kt], zN, 0, 0, 0);
            }
            aR[tl] = zR; aZ[tl] = zZ; aN[tl] = zN;
        }

        // ---- per tile: DPP redistribute, gates, quant, pack, write ----
        #pragma unroll
        for (int tl = 0; tl < TPW; ++tl) {
            // DPP redistribute: lane q*16+r*4+b <- reg r of lane q*16+b
            int vR = aR[tl][0], vZ = aZ[tl][0], vN = aN[tl][0];
            vR = __builtin_amdgcn_update_dpp(vR, aR[tl][1], 0x114, 0xF, 0x2, false);
            vR = __builtin_amdgcn_update_dpp(vR, aR[tl][2], 0x118, 0xF, 0x4, false);
            vR = __builtin_amdgcn_update_dpp(vR, aR[tl][3], 0x11C, 0xF, 0x8, false);
            vZ = __builtin_amdgcn_update_dpp(vZ, aZ[tl][1], 0x114, 0xF, 0x2, false);
            vZ = __builtin_amdgcn_update_dpp(vZ, aZ[tl][2], 0x118, 0xF, 0x4, false);
            vZ = __builtin_amdgcn_update_dpp(vZ, aZ[tl][3], 0x11C, 0xF, 0x8, false);
            vN = __builtin_amdgcn_update_dpp(vN, aN[tl][1], 0x114, 0xF, 0x2, false);
            vN = __builtin_amdgcn_update_dpp(vN, aN[tl][2], 0x118, 0xF, 0x4, false);
            vN = __builtin_amdgcn_update_dpp(vN, aN[tl][3], 0x11C, 0xF, 0x8, false);

            // dense dequant + gates (R14/R17 numerics, bit-identical)
            float pR = fmaf((float)vR, dqR[tl], baseR[tl]);
            float pZ = fmaf((float)vZ, dqZ[tl], baseZ[tl]);
            float pN = fmaf((float)vN, dqN[tl], baseN[tl]);

            float er = exp2_fast(fmaf(xv, wrS[tl], pR));
            float ez = exp2hw(fminf(fmaf(xv, wzS[tl], pZ), 14.0f));
            float dRd = 1.0f + er, dZd = 1.0f + ez;
            float qq = rcpf(dRd * dZd);
            float rrg = qq * dZd, zzg = qq * dRd;
            float gn = fmaf(rrg, pN, fmaf(xv, wnS[tl], bnI[tl]));
            float en = exp2hw(fminf(gn, 30.0f));
            float nn = fmaf(-2.0f, rcpf(1.0f + en), 1.0f);  // tanh
            h[tl] = fmaf(zzg, h[tl] - nn, nn);               // |h|<1

            int iq = (int)rintf(h[tl] * 127.0f);
            int hq = jv[tl] ? (iq & 255) : 0;
            // DPP gather (row_shl:4/8/12) + perm pack: bytes r=0..3
            int t1 = __builtin_amdgcn_update_dpp(0, hq, 0x104, 0xF, 0xF, true);
            int t2 = __builtin_amdgcn_update_dpp(0, hq, 0x108, 0xF, 0xF, true);
            int t3 = __builtin_amdgcn_update_dpp(0, hq, 0x10C, 0xF, 0xF, true);
            int p01 = __builtin_amdgcn_perm(t1, hq, 0x05010400);
            int p23 = __builtin_amdgcn_perm(t3, t2, 0x05010400);
            int pk  = __builtin_amdgcn_perm(p23, p01, 0x05040100);
            if (rr4 == 0)
                *(int*)(wb + woff[tl]) = pk;
        }
        __syncthreads();   // the only barrier per step
    };

    char* buf0 = hfr_s;
    char* buf1 = hfr_s + KT3 * FRAGB;
    for (int t = 0; t < T_LEN; t += 2) {
        step(buf0, buf1, t);
        step(buf1, buf0, t + 1);
    }

    // ---- final FC: publish h (f32) into x_s (x done), 40 lanes reduce ----
    __syncthreads();
    #pragma unroll
    for (int tl = 0; tl < TPW; ++tl)
        if (uu[tl] < PST) x_s[b * PST + uu[tl]] = h[tl];
    __syncthreads();
    if (tid < BB * 10) {
        int bb = tid / 10, c = tid % 10;
        float acc = b_fc[c];
        for (int k = 0; k < H; ++k)
            acc = fmaf(x_s[bb * PST + k], w_fc[c * H + k], acc);
        out[(b0 + bb) * 10 + c] = acc;
    }
}

extern "C" void kernel_launch(void* const* d_in, const int* in_sizes, int n_in,
                              void* d_out, int out_size, void* d_ws, size_t ws_size,
                              hipStream_t stream) {
    const float* x    = (const float*)d_in[0];
    const float* w_ih = (const float*)d_in[1];
    const float* w_hh = (const float*)d_in[2];
    const float* b_ih = (const float*)d_in[3];
    const float* b_hh = (const float*)d_in[4];
    const float* w_fc = (const float*)d_in[5];
    const float* b_fc = (const float*)d_in[6];
    float* out = (float*)d_out;

    gru_i8<<<NBLK, NTHR, 0, stream>>>(x, w_ih, w_hh, b_ih, b_hh, w_fc, b_fc, out);
}

// Round 6
// 670.187 us; speedup vs baseline: 1.3182x; 1.3182x over previous
//
#include <hip/hip_runtime.h>

#define H 181
#define T_LEN 1024
#define BB 4             // batch rows per block
#define NBLK 256         // 256 * 4 = 1024; one block per CU (LDS-pinned)
#define NTHR 768         // 12 waves, 3 per SIMD (R17 structure, measured 709us)
#define KT3 3            // k-tiles of 64 -> 192 >= 181
#define FRAGB 1024       // bytes per kt fragment (64 lanes x 16 B)
#define PST 192          // unit stride (wsc, FC)
#define XSTR 1027        // x_s stride (odd -> broadcast reads conflict-free)

typedef __attribute__((ext_vector_type(4))) int intx4;

#define LOG2E 1.4426950408889634f
// Schraudolph exp2 (balanced sawtooth, |rel err| <= ~3%), clamped to [-20,14]
#define SCH_C  1064992506.0f
#define SCH_LO 897220352.0f
#define SCH_HI 1182433024.0f

__device__ __forceinline__ float exp2_fast(float g) {
    float s = fmaf(g, 8388608.0f, SCH_C);
    s = fminf(fmaxf(s, SCH_LO), SCH_HI);
    return __uint_as_float((unsigned)s);
}
__device__ __forceinline__ float rcpf(float x)   { return __builtin_amdgcn_rcpf(x); }
__device__ __forceinline__ float exp2hw(float x) { return __builtin_amdgcn_exp2f(x); }

// R19: REVERT to 12-wave R17 structure (R18's 4-wave = 883us REGRESSION vs
// 709: MfmaUtil 20 + VALUBusy 45 at 1 wave/SIMD -> 35% stall; 12 waves were
// hiding latency, issue throughput [VALU-dominant ~2x MFMA] is the binding
// term). ONE change vs R17: the pack path. Per-lane ds_write_b8 at
// woff+rr4 replaces DPP-gather(3)+perm(3)+leader-b32; magic-number round
// (fma + float_as_int low byte, RNE-identical) replaces mul+rndne+cvt+and;
// jv select dropped (u>=H bytes only multiply zero-padded afr columns).
// ~8 of ~50 issue slots per tile-step removed. Numerics bit-identical.
__launch_bounds__(NTHR, 3)
__global__ void gru_i8(const float* __restrict__ x,
                       const float* __restrict__ w_ih,
                       const float* __restrict__ w_hh,
                       const float* __restrict__ b_ih,
                       const float* __restrict__ b_hh,
                       const float* __restrict__ w_fc,
                       const float* __restrict__ b_fc,
                       float* __restrict__ out) {
    __shared__ __align__(16) char  hfr_s[2 * KT3 * FRAGB];  // 6 KB i8 h dbuf
    __shared__ __align__(16) float x_s[BB * XSTR];          // 16 KB x; reused for FC
    __shared__ float wsc_s[3 * PST];                        // w_hh row scales
    __shared__ volatile char pad_s[57344];                  // total > 80 KB: pin 1 block/CU

    const int tid  = threadIdx.x;
    const int jt   = tid >> 6;          // wave = unit tile 0..11
    const int lane = tid & 63;
    const int col  = lane & 15;
    const int q    = lane >> 4;
    const int b0   = blockIdx.x * BB;
    if (tid == 0) pad_s[0] = 0;

    // ---- A fragments: per-row int8 w_hh, 3 gates x 3 kt (m = jt*16+col) ----
    // Built entirely in registers: dword = b0 | b1<<8 | b2<<16 | b3<<24.
    const int  mu = jt * 16 + col;
    const bool mv = (mu < H);
    intx4 afr[3][KT3];
    #pragma unroll
    for (int g = 0; g < 3; ++g) {
        const float* wrow = w_hh + (size_t)(g * H + (mv ? mu : 0)) * H;
        float rm = 0.0f;
        if (mv) for (int k = 0; k < H; ++k) rm = fmaxf(rm, fabsf(wrow[k]));
        float s    = (rm > 1e-30f) ? rm * (1.0f / 127.0f) : 1.0f;
        float invs = 1.0f / s;
        #pragma unroll
        for (int kt = 0; kt < KT3; ++kt) {
            intx4 frag;
            #pragma unroll
            for (int w = 0; w < 4; ++w) {
                int dw = 0;
                #pragma unroll
                for (int e = 0; e < 4; ++e) {
                    int k = kt * 64 + q * 16 + w * 4 + e;
                    float v = (mv && k < H) ? wrow[k] * invs : 0.0f;
                    v = fminf(fmaxf(rintf(v), -127.0f), 127.0f);
                    int iv = (int)v;
                    dw |= (iv & 255) << (8 * e);
                }
                frag[w] = dw;
            }
            afr[g][kt] = frag;
        }
        if (q == 0) wsc_s[g * PST + mu] = s;
    }

    // ---- stage x (stride 1027); zero h frag buffers ----
    for (int i = tid; i < BB * T_LEN; i += NTHR) {
        int bb = i >> 10, t = i & 1023;
        x_s[bb * XSTR + t] = x[(size_t)b0 * T_LEN + i];
    }
    {
        int* hz = (int*)hfr_s;
        for (int i = tid; i < 2 * KT3 * FRAGB / 4; i += NTHR) hz[i] = 0;
    }
    __syncthreads();   // wsc_s ready

    // ---- dense per-lane identity after DPP redistribute ----
    const int  rr4 = (col >> 2) & 3;       // reg index this lane receives
    const int  b   = col & 3;              // batch
    const int  u   = jt * 16 + q * 4 + rr4;  // unit
    const bool jv  = (u < H);
    const float dqR = -LOG2E * wsc_s[0 * PST + u] * (1.0f / 127.0f);
    const float dqZ = -LOG2E * wsc_s[1 * PST + u] * (1.0f / 127.0f);
    const float dqN =  2.0f * LOG2E * wsc_s[2 * PST + u] * (1.0f / 127.0f);
    const float baseR = jv ? -LOG2E * (b_ih[u] + b_hh[u])             : 0.0f;
    const float baseZ = jv ? -LOG2E * (b_ih[H + u] + b_hh[H + u])     : 0.0f;
    const float baseN = jv ?  2.0f * LOG2E * b_hh[2 * H + u]          : 0.0f;
    const float wrS = jv ? -LOG2E * w_ih[u]                : 0.0f;
    const float wzS = jv ? -LOG2E * w_ih[H + u]            : 0.0f;
    const float wnS = jv ?  2.0f * LOG2E * w_ih[2 * H + u] : 0.0f;
    const float bnI = jv ?  2.0f * LOG2E * b_ih[2 * H + u] : 0.0f;
    // per-lane byte slot in the fragment layout (this lane's unit u, batch b)
    const int wboff8 = (jt >> 2) * FRAGB + (((jt & 3) * 16 + b) * 16) + q * 4 + rr4;
    const int rbase = lane * 16;

    float h = 0.0f;

    auto step = [&](const char* rb, char* wb, int t) {
        intx4 bf[KT3];
        #pragma unroll
        for (int kt = 0; kt < KT3; ++kt)
            bf[kt] = *(const intx4*)(rb + kt * FRAGB + rbase);
        intx4 aR = {0,0,0,0}, aZ = {0,0,0,0}, aN = {0,0,0,0};
        #pragma unroll
        for (int kt = 0; kt < KT3; ++kt) {
            aR = __builtin_amdgcn_mfma_i32_16x16x64_i8(afr[0][kt], bf[kt], aR, 0, 0, 0);
            aZ = __builtin_amdgcn_mfma_i32_16x16x64_i8(afr[1][kt], bf[kt], aZ, 0, 0, 0);
            aN = __builtin_amdgcn_mfma_i32_16x16x64_i8(afr[2][kt], bf[kt], aN, 0, 0, 0);
        }

        // ---- DPP redistribute: lane q*16+r*4+b <- reg r of lane q*16+b ----
        int vR = aR[0], vZ = aZ[0], vN = aN[0];
        vR = __builtin_amdgcn_update_dpp(vR, aR[1], 0x114, 0xF, 0x2, false);
        vR = __builtin_amdgcn_update_dpp(vR, aR[2], 0x118, 0xF, 0x4, false);
        vR = __builtin_amdgcn_update_dpp(vR, aR[3], 0x11C, 0xF, 0x8, false);
        vZ = __builtin_amdgcn_update_dpp(vZ, aZ[1], 0x114, 0xF, 0x2, false);
        vZ = __builtin_amdgcn_update_dpp(vZ, aZ[2], 0x118, 0xF, 0x4, false);
        vZ = __builtin_amdgcn_update_dpp(vZ, aZ[3], 0x11C, 0xF, 0x8, false);
        vN = __builtin_amdgcn_update_dpp(vN, aN[1], 0x114, 0xF, 0x2, false);
        vN = __builtin_amdgcn_update_dpp(vN, aN[2], 0x118, 0xF, 0x4, false);
        vN = __builtin_amdgcn_update_dpp(vN, aN[3], 0x11C, 0xF, 0x8, false);

        // ---- dense dequant + gates (R14 numerics, bit-identical) ----
        float pR = fmaf((float)vR, dqR, baseR);
        float pZ = fmaf((float)vZ, dqZ, baseZ);
        float pN = fmaf((float)vN, dqN, baseN);
        float xv = x_s[b * XSTR + t];

        float er = exp2_fast(fmaf(xv, wrS, pR));
        float ez = exp2hw(fminf(fmaf(xv, wzS, pZ), 14.0f));
        float dR = 1.0f + er, dZ = 1.0f + ez;
        float qq = rcpf(dR * dZ);
        float rr = qq * dZ, zz = qq * dR;
        float gn = fmaf(rr, pN, fmaf(xv, wnS, bnI));
        float en = exp2hw(fminf(gn, 30.0f));
        float nn = fmaf(-2.0f, rcpf(1.0f + en), 1.0f);  // tanh
        h = fmaf(zz, h - nn, nn);                        // |h|<1

        // ---- quant + per-lane b8 write (magic RNE round; low byte = int8) ----
        // u>=H lanes write garbage bytes that only multiply zeroed afr cols.
        int hq = __float_as_int(fmaf(h, 127.0f, 12582912.0f));
        *(char*)(wb + wboff8) = (char)hq;
        __syncthreads();   // the only barrier per step
    };

    char* buf0 = hfr_s;
    char* buf1 = hfr_s + KT3 * FRAGB;
    for (int t = 0; t < T_LEN; t += 2) {
        step(buf0, buf1, t);
        step(buf1, buf0, t + 1);
    }

    // ---- final FC: publish h (f32) into x_s (x done), 40 lanes reduce ----
    __syncthreads();
    if (u < PST) x_s[b * PST + u] = h;
    __syncthreads();
    if (tid < BB * 10) {
        int bb = tid / 10, c = tid % 10;
        float acc = b_fc[c];
        for (int k = 0; k < H; ++k)
            acc = fmaf(x_s[bb * PST + k], w_fc[c * H + k], acc);
        out[(b0 + bb) * 10 + c] = acc;
    }
}

extern "C" void kernel_launch(void* const* d_in, const int* in_sizes, int n_in,
                              void* d_out, int out_size, void* d_ws, size_t ws_size,
                              hipStream_t stream) {
    const float* x    = (const float*)d_in[0];
    const float* w_ih = (const float*)d_in[1];
    const float* w_hh = (const float*)d_in[2];
    const float* b_ih = (const float*)d_in[3];
    const float* b_hh = (const float*)d_in[4];
    const float* w_fc = (const float*)d_in[5];
    const float* b_fc = (const float*)d_in[6];
    float* out = (float*)d_out;

    gru_i8<<<NBLK, NTHR, 0, stream>>>(x, w_ih, w_hh, b_ih, b_hh, w_fc, b_fc, out);
}